// Round 1
// baseline (4543.576 us; speedup 1.0000x reference)
//
#include <hip/hip_runtime.h>
#include <math.h>

#define B_    1024
#define VDIM  2048
#define NREG  49
#define HID   1024
#define NH    8
#define HD    128
#define ODIM  2048
#define TV    8

#define FMA4(accv, s, wv)                          \
    accv.x = fmaf(s, wv.x, accv.x);                \
    accv.y = fmaf(s, wv.y, accv.y);                \
    accv.z = fmaf(s, wv.z, accv.z);                \
    accv.w = fmaf(s, wv.w, accv.w)

// ---------------- Kernel A: qp = q @ Wq + bq  (B,1024)x(1024,1024) -------
// 256 blocks, 256 threads; each block: 4 batches x all 1024 cols (4/thread).
__global__ __launch_bounds__(256) void kA_qproj(
        const float* __restrict__ q, const float* __restrict__ Wq,
        const float* __restrict__ bq, float* __restrict__ qp) {
    __shared__ __align__(16) float qT[HID * 4];   // [k][b] transposed, 16 KB
    const int tid = threadIdx.x;
    const int b0 = blockIdx.x * 4;
    for (int i = tid; i < 4 * HID; i += 256) {
        int bb = i >> 10, k = i & (HID - 1);
        qT[k * 4 + bb] = q[(size_t)(b0 + bb) * HID + k];
    }
    __syncthreads();
    const float4* qT4 = (const float4*)qT;
    const float4* Wq4 = (const float4*)Wq;
    float4 a0 = {0,0,0,0}, a1 = {0,0,0,0}, a2 = {0,0,0,0}, a3 = {0,0,0,0};
    for (int k = 0; k < HID; ++k) {
        float4 qv = qT4[k];                         // broadcast: 4 batches at k
        float4 wv = Wq4[(size_t)k * (HID / 4) + tid]; // cols 4t..4t+3
        FMA4(a0, qv.x, wv);
        FMA4(a1, qv.y, wv);
        FMA4(a2, qv.z, wv);
        FMA4(a3, qv.w, wv);
    }
    const float4* bq4 = (const float4*)bq;
    float4 bqv = bq4[tid];
    float4* qp4 = (float4*)qp;
    float4 r;
    r.x = a0.x + bqv.x; r.y = a0.y + bqv.y; r.z = a0.z + bqv.z; r.w = a0.w + bqv.w;
    qp4[(size_t)(b0 + 0) * (HID / 4) + tid] = r;
    r.x = a1.x + bqv.x; r.y = a1.y + bqv.y; r.z = a1.z + bqv.z; r.w = a1.w + bqv.w;
    qp4[(size_t)(b0 + 1) * (HID / 4) + tid] = r;
    r.x = a2.x + bqv.x; r.y = a2.y + bqv.y; r.z = a2.z + bqv.z; r.w = a2.w + bqv.w;
    qp4[(size_t)(b0 + 2) * (HID / 4) + tid] = r;
    r.x = a3.x + bqv.x; r.y = a3.y + bqv.y; r.z = a3.z + bqv.z; r.w = a3.w + bqv.w;
    qp4[(size_t)(b0 + 3) * (HID / 4) + tid] = r;
}

// ---------------- Kernel B: per-batch fused attention --------------------
// grid = 1024 (one block per batch), block = 896 = 7 n-groups x 128 c-groups.
// Thread (ngrp,cg) owns regions n = 7*ngrp..7*ngrp+6 and columns
// {4cg..4cg+3} u {512+4cg..512+4cg+3}  (4+4 split -> 16B LDS lane stride).
__global__ __launch_bounds__(896) void kB_main(
        const float* __restrict__ visual, const float* __restrict__ Wv,
        const float* __restrict__ bv, const float* __restrict__ qp,
        const float* __restrict__ Wa, const float* __restrict__ ba,
        float* __restrict__ wout, float* __restrict__ att) {
    __shared__ __align__(16) float smemWv[TV * HID];   // 32 KB; reused as attp[7][1024]
    __shared__ __align__(16) float visT[NREG * TV];    // [n][vv]
    __shared__ float scoresL[NH * NREG];
    __shared__ float wtsL[NH * NREG];

    const int tid  = threadIdx.x;
    const int ngrp = tid >> 7;     // 0..6
    const int cg   = tid & 127;    // 0..127
    const int b    = blockIdx.x;

    const float* visB = visual + (size_t)b * (VDIM * NREG);

    float acc[56];                 // [nl][cl] nl=0..6, cl=0..7
    #pragma unroll
    for (int i = 0; i < 56; ++i) acc[i] = 0.f;

    float4* wv4s = (float4*)smemWv;
    const float4* visT4 = (const float4*)visT;

    #pragma unroll 1
    for (int t = 0; t < VDIM / TV; ++t) {
        const int v0 = t * TV;
        const float4* Wv4 = (const float4*)(Wv + (size_t)v0 * HID);
        for (int i = tid; i < TV * HID / 4; i += 896) wv4s[i] = Wv4[i];
        for (int j = tid; j < NREG * TV; j += 896) {
            int n = j % NREG, vv = j / NREG;
            visT[n * TV + vv] = visB[(size_t)(v0 + vv) * NREG + n];
        }
        __syncthreads();
        #pragma unroll
        for (int half = 0; half < 2; ++half) {
            float vr[28];
            #pragma unroll
            for (int nl = 0; nl < 7; ++nl) {
                float4 v4 = visT4[(ngrp * 7 + nl) * 2 + half];  // broadcast
                vr[nl * 4 + 0] = v4.x; vr[nl * 4 + 1] = v4.y;
                vr[nl * 4 + 2] = v4.z; vr[nl * 4 + 3] = v4.w;
            }
            #pragma unroll
            for (int vvl = 0; vvl < 4; ++vvl) {
                const int vv = half * 4 + vvl;
                float4 wa = wv4s[vv * 256 + cg];         // cols 4cg..4cg+3
                float4 wb = wv4s[vv * 256 + 128 + cg];   // cols 512+4cg..
                #pragma unroll
                for (int nl = 0; nl < 7; ++nl) {
                    float a = vr[nl * 4 + vvl];
                    acc[nl*8+0] = fmaf(a, wa.x, acc[nl*8+0]);
                    acc[nl*8+1] = fmaf(a, wa.y, acc[nl*8+1]);
                    acc[nl*8+2] = fmaf(a, wa.z, acc[nl*8+2]);
                    acc[nl*8+3] = fmaf(a, wa.w, acc[nl*8+3]);
                    acc[nl*8+4] = fmaf(a, wb.x, acc[nl*8+4]);
                    acc[nl*8+5] = fmaf(a, wb.y, acc[nl*8+5]);
                    acc[nl*8+6] = fmaf(a, wb.z, acc[nl*8+6]);
                    acc[nl*8+7] = fmaf(a, wb.w, acc[nl*8+7]);
                }
            }
        }
        __syncthreads();
    }

    // fold in bv -> acc becomes v_proj (without q_proj; q only enters tanh arg)
    const float4* bv4 = (const float4*)bv;
    const float4* qp4 = (const float4*)qp;
    const float4* Wa4 = (const float4*)Wa;
    const float4 bvA = bv4[cg],        bvB = bv4[128 + cg];
    const float4 qpA = qp4[(size_t)b * 256 + cg];
    const float4 qpB = qp4[(size_t)b * 256 + 128 + cg];
    const float4 wav = Wa4[cg & 31];   // Wa[(col)%128] identical for both halves
    #pragma unroll
    for (int nl = 0; nl < 7; ++nl) {
        acc[nl*8+0] += bvA.x; acc[nl*8+1] += bvA.y;
        acc[nl*8+2] += bvA.z; acc[nl*8+3] += bvA.w;
        acc[nl*8+4] += bvB.x; acc[nl*8+5] += bvB.y;
        acc[nl*8+6] += bvB.z; acc[nl*8+7] += bvB.w;
    }
    const float bas = ba[0];
    const int hA = cg >> 5, hB = 4 + (cg >> 5);
    #pragma unroll
    for (int nl = 0; nl < 7; ++nl) {
        float sA = tanhf(acc[nl*8+0] + qpA.x) * wav.x
                 + tanhf(acc[nl*8+1] + qpA.y) * wav.y
                 + tanhf(acc[nl*8+2] + qpA.z) * wav.z
                 + tanhf(acc[nl*8+3] + qpA.w) * wav.w;
        float sB = tanhf(acc[nl*8+4] + qpB.x) * wav.x
                 + tanhf(acc[nl*8+5] + qpB.y) * wav.y
                 + tanhf(acc[nl*8+6] + qpB.z) * wav.z
                 + tanhf(acc[nl*8+7] + qpB.w) * wav.w;
        #pragma unroll
        for (int off = 1; off < 32; off <<= 1) {    // reduce over 32-lane head group
            sA += __shfl_xor(sA, off);
            sB += __shfl_xor(sB, off);
        }
        if ((cg & 31) == 0) {
            int n = ngrp * 7 + nl;
            scoresL[hA * NREG + n] = sA + bas;
            scoresL[hB * NREG + n] = sB + bas;
        }
    }
    __syncthreads();
    if (tid < NH) {
        float m = -1e30f;
        for (int n = 0; n < NREG; ++n) m = fmaxf(m, scoresL[tid * NREG + n]);
        float s = 0.f;
        for (int n = 0; n < NREG; ++n) {
            float e = expf(scoresL[tid * NREG + n] - m);
            wtsL[tid * NREG + n] = e; s += e;
        }
        float inv = 1.f / s;
        for (int n = 0; n < NREG; ++n) {
            float w = wtsL[tid * NREG + n] * inv;
            wtsL[tid * NREG + n] = w;
            wout[(size_t)b * (NH * NREG) + tid * NREG + n] = w;
        }
    }
    __syncthreads();
    // attended partials over this thread's 7 regions
    float atA0=0,atA1=0,atA2=0,atA3=0, atB0=0,atB1=0,atB2=0,atB3=0;
    #pragma unroll
    for (int nl = 0; nl < 7; ++nl) {
        int n = ngrp * 7 + nl;
        float wA = wtsL[hA * NREG + n], wB = wtsL[hB * NREG + n];
        atA0 = fmaf(wA, acc[nl*8+0], atA0);
        atA1 = fmaf(wA, acc[nl*8+1], atA1);
        atA2 = fmaf(wA, acc[nl*8+2], atA2);
        atA3 = fmaf(wA, acc[nl*8+3], atA3);
        atB0 = fmaf(wB, acc[nl*8+4], atB0);
        atB1 = fmaf(wB, acc[nl*8+5], atB1);
        atB2 = fmaf(wB, acc[nl*8+6], atB2);
        atB3 = fmaf(wB, acc[nl*8+7], atB3);
    }
    float4* attp4 = (float4*)smemWv;   // reuse GEMM buffer: attp[7][1024]
    float4 pa; pa.x=atA0; pa.y=atA1; pa.z=atA2; pa.w=atA3;
    float4 pb; pb.x=atB0; pb.y=atB1; pb.z=atB2; pb.w=atB3;
    attp4[ngrp * 256 + cg] = pa;
    attp4[ngrp * 256 + 128 + cg] = pb;
    __syncthreads();
    for (int c = tid; c < HID; c += 896) {
        float s = 0.f;
        #pragma unroll
        for (int g = 0; g < 7; ++g) s += smemWv[g * HID + c];
        att[(size_t)b * HID + c] = s;
    }
}

// ---------------- Kernel C: out = att @ Wo + bo  (1024,1024)x(1024,2048) --
// grid = 512: 256 batch-groups(4) x 2 col-groups(1024). 256 thr, 4 cols each.
__global__ __launch_bounds__(256) void kC_outproj(
        const float* __restrict__ att, const float* __restrict__ Wo,
        const float* __restrict__ bo, float* __restrict__ out) {
    __shared__ __align__(16) float attT[HID * 4];   // [k][b]
    const int tid = threadIdx.x;
    const int bgrp = blockIdx.x >> 1, cgrp = blockIdx.x & 1;
    const int b0 = bgrp * 4;
    for (int i = tid; i < 4 * HID; i += 256) {
        int bb = i >> 10, k = i & (HID - 1);
        attT[k * 4 + bb] = att[(size_t)(b0 + bb) * HID + k];
    }
    __syncthreads();
    const float4* attT4 = (const float4*)attT;
    const float4* Wo4 = (const float4*)Wo;
    float4 a0 = {0,0,0,0}, a1 = {0,0,0,0}, a2 = {0,0,0,0}, a3 = {0,0,0,0};
    const int cbase = cgrp * 256 + tid;   // float4 column index
    for (int k = 0; k < HID; ++k) {
        float4 av = attT4[k];
        float4 wv = Wo4[(size_t)k * (ODIM / 4) + cbase];
        FMA4(a0, av.x, wv);
        FMA4(a1, av.y, wv);
        FMA4(a2, av.z, wv);
        FMA4(a3, av.w, wv);
    }
    const float4* bo4 = (const float4*)bo;
    float4 bov = bo4[cbase];
    float4* out4 = (float4*)out;
    float4 r;
    r.x = a0.x + bov.x; r.y = a0.y + bov.y; r.z = a0.z + bov.z; r.w = a0.w + bov.w;
    out4[(size_t)(b0 + 0) * (ODIM / 4) + cbase] = r;
    r.x = a1.x + bov.x; r.y = a1.y + bov.y; r.z = a1.z + bov.z; r.w = a1.w + bov.w;
    out4[(size_t)(b0 + 1) * (ODIM / 4) + cbase] = r;
    r.x = a2.x + bov.x; r.y = a2.y + bov.y; r.z = a2.z + bov.z; r.w = a2.w + bov.w;
    out4[(size_t)(b0 + 2) * (ODIM / 4) + cbase] = r;
    r.x = a3.x + bov.x; r.y = a3.y + bov.y; r.z = a3.z + bov.z; r.w = a3.w + bov.w;
    out4[(size_t)(b0 + 3) * (ODIM / 4) + cbase] = r;
}

extern "C" void kernel_launch(void* const* d_in, const int* in_sizes, int n_in,
                              void* d_out, int out_size, void* d_ws, size_t ws_size,
                              hipStream_t stream) {
    const float* visual = (const float*)d_in[0];  // (1024,2048,7,7)
    const float* qf     = (const float*)d_in[1];  // (1024,1024)
    const float* Wv     = (const float*)d_in[2];  // (2048,1024)
    const float* bv     = (const float*)d_in[3];  // (1024)
    const float* Wq     = (const float*)d_in[4];  // (1024,1024)
    const float* bq     = (const float*)d_in[5];  // (1024)
    const float* Wa     = (const float*)d_in[6];  // (128)
    const float* ba     = (const float*)d_in[7];  // ()
    const float* Wo     = (const float*)d_in[8];  // (1024,2048)
    const float* bo     = (const float*)d_in[9];  // (2048)

    float* out  = (float*)d_out;                  // (1024,2048)
    float* wout = out + (size_t)B_ * ODIM;        // (1024,8,49)

    float* qp  = (float*)d_ws;                    // (1024,1024)
    float* att = qp + (size_t)B_ * HID;           // (1024,1024)

    kA_qproj<<<B_ / 4, 256, 0, stream>>>(qf, Wq, bq, qp);
    kB_main<<<B_, 896, 0, stream>>>(visual, Wv, bv, qp, Wa, ba, wout, att);
    kC_outproj<<<(B_ / 4) * 2, 256, 0, stream>>>(att, Wo, bo, out);
}

// Round 5
// 1122.102 us; speedup vs baseline: 4.0492x; 4.0492x over previous
//
#include <hip/hip_runtime.h>
#include <math.h>

#define B_    1024
#define VDIM  2048
#define NREG  49
#define HID   1024
#define ODIM  2048

typedef _Float16 half8 __attribute__((ext_vector_type(8)));
typedef float f32x4 __attribute__((ext_vector_type(4)));

typedef __attribute__((address_space(1))) const unsigned int GU32;
typedef __attribute__((address_space(3))) unsigned int LU32;

__device__ __forceinline__ void gload_lds16(const void* g, void* l) {
    __builtin_amdgcn_global_load_lds((GU32*)g, (LU32*)l, 16, 0, 0);
}

#define FMA4(accv, s, wv)                          \
    accv.x = fmaf(s, wv.x, accv.x);                \
    accv.y = fmaf(s, wv.y, accv.y);                \
    accv.z = fmaf(s, wv.z, accv.z);                \
    accv.w = fmaf(s, wv.w, accv.w)

// ---------------- Prep: pack Wv (2048x1024 f32, n-contig) into fragment-
// linear fp16 blobs: [kstep 0..63][nhalf 0..1][frag f=w*4+bn 0..31][lane][8]
// n = nh*512 + w*64 + bn*16 + (l&15);  k = ks*32 + (l>>4)*8 + t
__global__ __launch_bounds__(512) void kPrepW(
        const float* __restrict__ Wv, _Float16* __restrict__ Wpk) {
    const int g = blockIdx.x * 512 + threadIdx.x;   // 0..262143
    const int l  = g & 63;
    const int f  = (g >> 6) & 31;
    const int nh = (g >> 11) & 1;
    const int ks = g >> 12;                         // 0..63
    const int wv = f >> 2, bn = f & 3;
    const int n  = nh * 512 + wv * 64 + bn * 16 + (l & 15);
    const int k0 = ks * 32 + (l >> 4) * 8;
    half8 hv;
    #pragma unroll
    for (int t = 0; t < 8; ++t) hv[t] = (_Float16)Wv[(size_t)(k0 + t) * HID + n];
    *(half8*)(Wpk + (size_t)g * 8) = hv;
}

// ---------------- Kernel A: qp = q @ Wq + bq (fp32 VALU, small) ----------
__global__ __launch_bounds__(256) void kA_qproj(
        const float* __restrict__ q, const float* __restrict__ Wq,
        const float* __restrict__ bq, float* __restrict__ qp) {
    __shared__ __align__(16) float qT[HID * 4];
    const int tid = threadIdx.x;
    const int b0 = blockIdx.x * 4;
    for (int i = tid; i < 4 * HID; i += 256) {
        int bb = i >> 10, k = i & (HID - 1);
        qT[k * 4 + bb] = q[(size_t)(b0 + bb) * HID + k];
    }
    __syncthreads();
    const float4* qT4 = (const float4*)qT;
    const float4* Wq4 = (const float4*)Wq;
    float4 a0 = {0,0,0,0}, a1 = {0,0,0,0}, a2 = {0,0,0,0}, a3 = {0,0,0,0};
    for (int k = 0; k < HID; ++k) {
        float4 qv = qT4[k];
        float4 wv = Wq4[(size_t)k * (HID / 4) + tid];
        FMA4(a0, qv.x, wv);
        FMA4(a1, qv.y, wv);
        FMA4(a2, qv.z, wv);
        FMA4(a3, qv.w, wv);
    }
    const float4* bq4 = (const float4*)bq;
    float4 bqv = bq4[tid];
    float4* qp4 = (float4*)qp;
    float4 r;
    r.x = a0.x + bqv.x; r.y = a0.y + bqv.y; r.z = a0.z + bqv.z; r.w = a0.w + bqv.w;
    qp4[(size_t)(b0 + 0) * (HID / 4) + tid] = r;
    r.x = a1.x + bqv.x; r.y = a1.y + bqv.y; r.z = a1.z + bqv.z; r.w = a1.w + bqv.w;
    qp4[(size_t)(b0 + 1) * (HID / 4) + tid] = r;
    r.x = a2.x + bqv.x; r.y = a2.y + bqv.y; r.z = a2.z + bqv.z; r.w = a2.w + bqv.w;
    qp4[(size_t)(b0 + 2) * (HID / 4) + tid] = r;
    r.x = a3.x + bqv.x; r.y = a3.y + bqv.y; r.z = a3.z + bqv.z; r.w = a3.w + bqv.w;
    qp4[(size_t)(b0 + 3) * (HID / 4) + tid] = r;
}

// ---------------- Kernel B: MFMA fp16 v_proj GEMM + fused attention ------
// grid 2048: block = (batch, nhalf); 512 thr = 8 waves; wave tile M64 x N64.
// MFMA 16x16x32 f16: A lane: m=l&15, k=8*(l>>4)+j; B lane: n=l&15, same k;
// C/D: col=l&15, row=4*(l>>4)+reg (guide-verified, dtype-independent).
__global__ __launch_bounds__(512, 4) void kB_mfma(
        const float* __restrict__ visual, const _Float16* __restrict__ Wpk,
        const float* __restrict__ bv, const float* __restrict__ qp,
        const float* __restrict__ Wa, const float* __restrict__ ba,
        float* __restrict__ wout, float* __restrict__ att) {
    __shared__ __align__(16) _Float16 Blds[32 * 64 * 8];   // 32 KB frag-linear
    __shared__ __align__(16) _Float16 Alds[4 * 64 * 8];    // 4 KB frag-linear
    __shared__ float scoreP[8 * 64];
    __shared__ float wts[4 * 64];

    const int tid  = threadIdx.x;
    const int lane = tid & 63;
    const int w    = tid >> 6;                    // wave 0..7
    const int bid  = blockIdx.x;
    const int batch = ((bid >> 4) << 3) + (bid & 7);  // both nhalves same XCD
    const int nhalf = (bid >> 3) & 1;

    // zero A_lds once: slots for m=49..63 stay 0 forever
    {
        unsigned int* a32 = (unsigned int*)Alds;
        for (int i = tid; i < 1024; i += 512) a32[i] = 0u;
    }
    __syncthreads();

    const float* visB = visual + (size_t)batch * (VDIM * NREG);

    // A-staging assignment: tid<196 handles (n = tid%49, koct = tid/49)
    const bool astage = (tid < 196);
    const int an = tid % 49, akoct = tid / 49;          // koct 0..3
    const int aam = an >> 4;
    const int alane = (an & 15) + (akoct << 4);
    _Float16* adst = &Alds[(aam * 64 + alane) * 8];
    const float* asrc_base = visB + (size_t)(akoct * 8) * NREG + an;

    f32x4 acc[4][4];
    #pragma unroll
    for (int am = 0; am < 4; ++am)
        #pragma unroll
        for (int bn = 0; bn < 4; ++bn)
            acc[am][bn] = (f32x4){0.f, 0.f, 0.f, 0.f};

    const char* bdst0 = (const char*)Blds + tid * 16;

    #pragma unroll 1
    for (int s = 0; s < 64; ++s) {
        // B: 32 KB fragment-linear blob -> LDS, direct DMA (width 16)
        const char* bsrc = (const char*)(Wpk + ((size_t)(s * 2 + nhalf)) * 16384) + tid * 16;
        #pragma unroll
        for (int r = 0; r < 4; ++r)
            gload_lds16(bsrc + r * 8192, (void*)(bdst0 + r * 8192));
        // A: read 8 fp32 (coalesced across lanes), cvt, one b128 write
        if (astage) {
            const float* asrc = asrc_base + (size_t)s * 32 * NREG;
            half8 hv;
            #pragma unroll
            for (int t = 0; t < 8; ++t) hv[t] = (_Float16)asrc[(size_t)t * NREG];
            *(half8*)adst = hv;
        }
        __syncthreads();
        half8 bfr[4];
        #pragma unroll
        for (int bn = 0; bn < 4; ++bn)
            bfr[bn] = *(const half8*)&Blds[((w * 4 + bn) * 64 + lane) * 8];
        #pragma unroll
        for (int am = 0; am < 4; ++am) {
            half8 afr = *(const half8*)&Alds[(am * 64 + lane) * 8];
            #pragma unroll
            for (int bn = 0; bn < 4; ++bn)
                acc[am][bn] = __builtin_amdgcn_mfma_f32_16x16x32_f16(
                                  afr, bfr[bn], acc[am][bn], 0, 0, 0);
        }
        __syncthreads();
    }

    // ---------- fused attention epilogue ----------
    const int l15 = lane & 15, lg = lane >> 4;
    float bvv[4], qpv[4], wav[4];
    #pragma unroll
    for (int bn = 0; bn < 4; ++bn) {
        int ng = nhalf * 512 + w * 64 + bn * 16 + l15;
        bvv[bn] = bv[ng];
        qpv[bn] = qp[(size_t)batch * HID + ng];
        wav[bn] = Wa[(w & 1) * 64 + bn * 16 + l15];
    }
    #pragma unroll
    for (int am = 0; am < 4; ++am)
        #pragma unroll
        for (int bn = 0; bn < 4; ++bn)
            #pragma unroll
            for (int r = 0; r < 4; ++r)
                acc[am][bn][r] += bvv[bn];          // acc := v_proj

    // scores: per row m = am*16 + lg*4 + r, 16-lane d-reduce per wave-half
    #pragma unroll
    for (int am = 0; am < 4; ++am) {
        #pragma unroll
        for (int r = 0; r < 4; ++r) {
            float p = 0.f;
            #pragma unroll
            for (int bn = 0; bn < 4; ++bn) {
                float x = acc[am][bn][r] + qpv[bn];
                float e = __expf(2.f * x);
                float th = __fdividef(e - 1.f, e + 1.f);   // tanh(x)
                p = fmaf(th, wav[bn], p);
            }
            p += __shfl_xor(p, 1); p += __shfl_xor(p, 2);
            p += __shfl_xor(p, 4); p += __shfl_xor(p, 8);
            if (l15 == am * 4 + r) scoreP[w * 64 + am * 16 + lg * 4 + r] = p;
        }
    }
    __syncthreads();
    // softmax: wave h<4 owns local head h (waves 2h, 2h+1 hold its d-halves)
    if (w < 4) {
        float sv = scoreP[(w * 2) * 64 + lane] + scoreP[(w * 2 + 1) * 64 + lane] + ba[0];
        const bool valid = lane < NREG;
        float mx = valid ? sv : -1e30f;
        #pragma unroll
        for (int off = 32; off >= 1; off >>= 1) mx = fmaxf(mx, __shfl_xor(mx, off));
        float e = valid ? __expf(sv - mx) : 0.f;
        float sm = e;
        #pragma unroll
        for (int off = 32; off >= 1; off >>= 1) sm += __shfl_xor(sm, off);
        float wt = e / sm;
        wts[w * 64 + lane] = wt;                     // 0 for m>=49
        if (valid)
            wout[(size_t)batch * (8 * NREG) + (nhalf * 4 + w) * NREG + lane] = wt;
    }
    __syncthreads();
    // attended: per-lane partial over its 16 rows, reduce across lane-groups
    float at[4] = {0.f, 0.f, 0.f, 0.f};
    const int hl = w >> 1;
    #pragma unroll
    for (int am = 0; am < 4; ++am)
        #pragma unroll
        for (int r = 0; r < 4; ++r) {
            float wt = wts[hl * 64 + am * 16 + lg * 4 + r];
            #pragma unroll
            for (int bn = 0; bn < 4; ++bn) at[bn] = fmaf(wt, acc[am][bn][r], at[bn]);
        }
    #pragma unroll
    for (int bn = 0; bn < 4; ++bn) {
        at[bn] += __shfl_xor(at[bn], 16);
        at[bn] += __shfl_xor(at[bn], 32);
    }
    if (lane < 16) {
        #pragma unroll
        for (int bn = 0; bn < 4; ++bn)
            att[(size_t)batch * HID + nhalf * 512 + w * 64 + bn * 16 + lane] = at[bn];
    }
}

// ---------------- Kernel C: out = att @ Wo + bo (fp32 VALU) --------------
__global__ __launch_bounds__(256) void kC_outproj(
        const float* __restrict__ att, const float* __restrict__ Wo,
        const float* __restrict__ bo, float* __restrict__ out) {
    __shared__ __align__(16) float attT[HID * 4];
    const int tid = threadIdx.x;
    const int bgrp = blockIdx.x >> 1, cgrp = blockIdx.x & 1;
    const int b0 = bgrp * 4;
    for (int i = tid; i < 4 * HID; i += 256) {
        int bb = i >> 10, k = i & (HID - 1);
        attT[k * 4 + bb] = att[(size_t)(b0 + bb) * HID + k];
    }
    __syncthreads();
    const float4* attT4 = (const float4*)attT;
    const float4* Wo4 = (const float4*)Wo;
    float4 a0 = {0,0,0,0}, a1 = {0,0,0,0}, a2 = {0,0,0,0}, a3 = {0,0,0,0};
    const int cbase = cgrp * 256 + tid;
    for (int k = 0; k < HID; ++k) {
        float4 av = attT4[k];
        float4 wv = Wo4[(size_t)k * (ODIM / 4) + cbase];
        FMA4(a0, av.x, wv);
        FMA4(a1, av.y, wv);
        FMA4(a2, av.z, wv);
        FMA4(a3, av.w, wv);
    }
    const float4* bo4 = (const float4*)bo;
    float4 bov = bo4[cbase];
    float4* out4 = (float4*)out;
    float4 r;
    r.x = a0.x + bov.x; r.y = a0.y + bov.y; r.z = a0.z + bov.z; r.w = a0.w + bov.w;
    out4[(size_t)(b0 + 0) * (ODIM / 4) + cbase] = r;
    r.x = a1.x + bov.x; r.y = a1.y + bov.y; r.z = a1.z + bov.z; r.w = a1.w + bov.w;
    out4[(size_t)(b0 + 1) * (ODIM / 4) + cbase] = r;
    r.x = a2.x + bov.x; r.y = a2.y + bov.y; r.z = a2.z + bov.z; r.w = a2.w + bov.w;
    out4[(size_t)(b0 + 2) * (ODIM / 4) + cbase] = r;
    r.x = a3.x + bov.x; r.y = a3.y + bov.y; r.z = a3.z + bov.z; r.w = a3.w + bov.w;
    out4[(size_t)(b0 + 3) * (ODIM / 4) + cbase] = r;
}

extern "C" void kernel_launch(void* const* d_in, const int* in_sizes, int n_in,
                              void* d_out, int out_size, void* d_ws, size_t ws_size,
                              hipStream_t stream) {
    const float* visual = (const float*)d_in[0];  // (1024,2048,7,7)
    const float* qf     = (const float*)d_in[1];  // (1024,1024)
    const float* Wv     = (const float*)d_in[2];  // (2048,1024)
    const float* bv     = (const float*)d_in[3];  // (1024)
    const float* Wq     = (const float*)d_in[4];  // (1024,1024)
    const float* bq     = (const float*)d_in[5];  // (1024)
    const float* Wa     = (const float*)d_in[6];  // (128)
    const float* ba     = (const float*)d_in[7];  // ()
    const float* Wo     = (const float*)d_in[8];  // (1024,2048)
    const float* bo     = (const float*)d_in[9];  // (2048)

    float* out  = (float*)d_out;                  // (1024,2048)
    float* wout = out + (size_t)B_ * ODIM;        // (1024,8,49)

    float* qp  = (float*)d_ws;                    // 4 MB
    float* att = qp + (size_t)B_ * HID;           // 4 MB
    _Float16* Wpk = (_Float16*)(att + (size_t)B_ * HID);  // 4 MB packed Wv

    kPrepW<<<512, 512, 0, stream>>>(Wv, Wpk);
    kA_qproj<<<B_ / 4, 256, 0, stream>>>(qf, Wq, bq, qp);
    kB_mfma<<<2048, 512, 0, stream>>>(visual, Wpk, bv, qp, Wa, ba, wout, att);
    kC_outproj<<<(B_ / 4) * 2, 256, 0, stream>>>(att, Wo, bo, out);
}